// Round 17
// baseline (350.949 us; speedup 1.0000x reference)
//
#include <hip/hip_runtime.h>
#include <math.h>

#define LN2F 0.6931471805599453f
#define LOG2EF 1.4426950408889634f

typedef _Float16 half_t;
typedef _Float16 half4_t __attribute__((ext_vector_type(4)));
typedef _Float16 half8_t __attribute__((ext_vector_type(8)));
typedef __fp16 fp16x2 __attribute__((ext_vector_type(2)));
typedef __fp16 fp16x4 __attribute__((ext_vector_type(4)));
typedef __fp16 fp16x8 __attribute__((ext_vector_type(8)));
typedef float f32x4 __attribute__((ext_vector_type(4)));

__device__ __forceinline__ float sspf(float z) {
    return fmaxf(z, 0.f) + __logf(1.f + __expf(-fabsf(z))) - LN2F;
}
__device__ __forceinline__ half4_t cvt4(float x, float y, float z, float w) {
    half4_t r; r[0]=(half_t)x; r[1]=(half_t)y; r[2]=(half_t)z; r[3]=(half_t)w; return r;
}
__device__ __forceinline__ half8_t pk8(float a, float b, float c, float d,
                                       float e, float f, float g, float h) {
    fp16x2 p0 = __builtin_amdgcn_cvt_pkrtz(a, b);
    fp16x2 p1 = __builtin_amdgcn_cvt_pkrtz(c, d);
    fp16x2 p2 = __builtin_amdgcn_cvt_pkrtz(e, f);
    fp16x2 p3 = __builtin_amdgcn_cvt_pkrtz(g, h);
    fp16x4 lo = __builtin_shufflevector(p0, p1, 0, 1, 2, 3);
    fp16x4 hi = __builtin_shufflevector(p2, p3, 0, 1, 2, 3);
    fp16x8 v  = __builtin_shufflevector(lo, hi, 0, 1, 2, 3, 4, 5, 6, 7);
    return __builtin_bit_cast(half8_t, v);
}

// async global->LDS DMA, 16 B per lane; dest = wave-uniform base + lane*16
__device__ __forceinline__ void load_lds16(const void* g, void* l) {
    __builtin_amdgcn_global_load_lds(
        (const __attribute__((address_space(1))) unsigned int*)g,
        (__attribute__((address_space(3))) unsigned int*)l, 16, 0, 0);
}

__device__ __forceinline__ int lbound(const int* __restrict__ a, int n, int key) {
    int lo = 0, hi = n;
    while (lo < hi) { int m = (lo + hi) >> 1; if (a[m] < key) lo = m + 1; else hi = m; }
    return lo;
}

// ---- weight prep (layouts validated R12/R13) ----
__global__ __launch_bounds__(256) void prep_weights(
    const float* __restrict__ W_in2f, const float* __restrict__ W_f1,
    const float* __restrict__ W_f2, const float* __restrict__ W_o1,
    const float* __restrict__ W_o2,
    const float* __restrict__ b_f1, const float* __restrict__ b_f2,
    half_t* __restrict__ Wt_in2f, half_t* __restrict__ Wt_f1,
    half_t* __restrict__ W2L, half_t* __restrict__ Wt_o1,
    half_t* __restrict__ Wt_o2, float* __restrict__ b1sc, float* __restrict__ b2a)
{
    int b = blockIdx.x;
    if (b < 64) {
        int i = b*256 + threadIdx.x;
        Wt_in2f[i] = (half_t)W_in2f[(i & 127)*128 + (i >> 7)];
    } else if (b < 80) {
        int i = (b-64)*256 + threadIdx.x;
        int n = i >> 5, k = i & 31;
        Wt_f1[i] = (k < 20) ? (half_t)W_f1[k*128 + n] : (half_t)0.f;
    } else if (b < 144) {
        int i = (b-80)*256 + threadIdx.x;     // 0..16383
        int j = i & 7, ln = (i >> 3) & 15, g = (i >> 7) & 3;
        int nt = (i >> 9) & 7, t = i >> 12;
        int k = 32*t + ((j < 4) ? (g*4 + j) : (16 + g*4 + (j - 4)));
        W2L[i] = (half_t)(LN2F * W_f2[k*128 + ln*8 + nt]);
    } else if (b < 208) {
        int i = (b-144)*256 + threadIdx.x;
        Wt_o1[i] = (half_t)W_o1[(i & 127)*128 + (i >> 7)];
    } else if (b < 272) {
        int i = (b-208)*256 + threadIdx.x;
        Wt_o2[i] = (half_t)W_o2[(i & 127)*128 + (i >> 7)];
    } else {
        int c = threadIdx.x;
        if (c < 128) {
            float s = 0.f;
            for (int k = 0; k < 128; ++k) s += W_f2[k*128 + c];
            b2a[c]  = b_f2[c] - LN2F * s;
            b1sc[c] = b_f1[c] * LOG2EF;
        }
    }
}

// atom_start[a] = first edge index with idx_i >= a; atom_start[N] = E
__global__ __launch_bounds__(256) void seg_starts(
    const int* __restrict__ idx_i, int* __restrict__ atom_start, int E, int N)
{
    int e = blockIdx.x * 256 + threadIdx.x;
    if (e >= E) return;
    int a = idx_i[e];
    int prev = (e == 0) ? -1 : idx_i[e - 1];
    for (int k = prev + 1; k <= a; ++k) atom_start[k] = e;
    if (e == E - 1)
        for (int k = a + 1; k <= N; ++k) atom_start[k] = E;
}

// chunk_off = prefix sum of per-atom chunk counts (>=1 per atom); single block.
__global__ __launch_bounds__(256) void chunk_scan(
    const int* __restrict__ atom_start, int* __restrict__ chunk_off, int N)
{
    __shared__ int part[256];
    __shared__ int base[257];
    int t = threadIdx.x;
    int L = (N + 255) / 256;
    int lo = min(t * L, N), hi = min(lo + L, N);
    int s = 0;
    for (int a = lo; a < hi; ++a) {
        int deg = atom_start[a+1] - atom_start[a];
        s += max(1, (deg + 15) >> 4);
    }
    part[t] = s;
    __syncthreads();
    if (t == 0) {
        int acc = 0;
        for (int i = 0; i < 256; ++i) { base[i] = acc; acc += part[i]; }
        base[256] = acc;
    }
    __syncthreads();
    int run = base[t];
    for (int a = lo; a < hi; ++a) {
        chunk_off[a] = run;
        int deg = atom_start[a+1] - atom_start[a];
        run += max(1, (deg + 15) >> 4);
    }
    if (t == 0) chunk_off[N] = base[256];
}

// per-atom: write chunk metadata (cs, atom<<6 | cnt<<1 | isLast)
__global__ __launch_bounds__(256) void chunk_atoms(
    const int* __restrict__ atom_start, const int* __restrict__ chunk_off,
    int2* __restrict__ cmeta, int N)
{
    int a = blockIdx.x * 256 + threadIdx.x;
    if (a >= N) return;
    int s = atom_start[a], e1 = atom_start[a+1];
    int c0 = chunk_off[a], nc = chunk_off[a+1] - c0;
    for (int k = 0; k < nc; ++k) {
        int cs = s + 16*k;
        int cnt = e1 - cs; cnt = cnt < 0 ? 0 : (cnt > 16 ? 16 : cnt);
        cmeta[c0+k] = make_int2(cs, (a << 6) | (cnt << 1) | (k == nc-1 ? 1 : 0));
    }
}

// per (chunk, slot): pre-padded jv byte-offsets (DMA order); also zero-pads
// cmeta beyond NC (prefetch reads up to NC+1 -> must not see poison).
__global__ __launch_bounds__(256) void chunk_edges(
    const int* __restrict__ idx_j, const int* __restrict__ chunk_off,
    int2* __restrict__ cmeta, int* __restrict__ jvpk, int N, int ncmax)
{
    int i = blockIdx.x * 256 + threadIdx.x;
    if (i >= ncmax * 16) return;
    int c = i >> 4, s = i & 15;
    int NC = chunk_off[N];
    if (c >= NC) {
        jvpk[i] = 0;
        if (s == 0) cmeta[c] = make_int2(0, 0);   // pad: cs=0, cnt=0, no flush
        return;
    }
    int2 m = cmeta[c];
    int cnt = (m.y >> 1) & 31;
    int off = 4*(s & 3) + (s >> 2);                        // edge = cs + 4*it + g
    jvpk[i] = (off < cnt) ? (idx_j[m.x + off] << 8) : 0;   // byte offset (row*256)
}

// h = x @ W_in2f -> f16
__global__ __launch_bounds__(256) void mfma_gemm_h(
    const float* __restrict__ A, const half_t* __restrict__ Bt,
    half_t* __restrict__ Ch, int nrows)
{
    const int tid = threadIdx.x;
    const int w = tid >> 6, l = tid & 63, g = l >> 4, ln = l & 15;
    const int r0 = blockIdx.x * 64;

    f32x4 acc[4][2];
    #pragma unroll
    for (int rf = 0; rf < 4; ++rf)
        #pragma unroll
        for (int cf = 0; cf < 2; ++cf) acc[rf][cf] = (f32x4)0.f;

    #pragma unroll
    for (int kk = 0; kk < 8; ++kk) {
        const int kb = kk * 16 + g * 4;
        half4_t a[4];
        #pragma unroll
        for (int rf = 0; rf < 4; ++rf) {
            int r = r0 + rf * 16 + ln;
            int rr = r < nrows ? r : nrows - 1;
            float4 av = *(const float4*)(A + (size_t)rr * 128 + kb);
            a[rf] = cvt4(av.x, av.y, av.z, av.w);
        }
        #pragma unroll
        for (int cf = 0; cf < 2; ++cf) {
            int n = w * 32 + cf * 16 + ln;
            half4_t b = *(const half4_t*)(Bt + (size_t)n * 128 + kb);
            #pragma unroll
            for (int rf = 0; rf < 4; ++rf)
                acc[rf][cf] = __builtin_amdgcn_mfma_f32_16x16x16f16(a[rf], b, acc[rf][cf], 0, 0, 0);
        }
    }
    #pragma unroll
    for (int cf = 0; cf < 2; ++cf) {
        int n = w * 32 + cf * 16 + ln;
        #pragma unroll
        for (int rf = 0; rf < 4; ++rf)
            #pragma unroll
            for (int reg = 0; reg < 4; ++reg) {
                int r = r0 + rf * 16 + g * 4 + reg;
                if (r < nrows) Ch[(size_t)r * 128 + n] = (half_t)acc[rf][cf][reg];
            }
    }
}

// fused out-MLP: out = ssp(agg@O1+b1)@O2+b2
__global__ __launch_bounds__(256) void mfma_gemm2(
    const float* __restrict__ A, const half_t* __restrict__ Bt1,
    const float* __restrict__ bias1, const half_t* __restrict__ Bt2,
    const float* __restrict__ bias2, float* __restrict__ out, int nrows)
{
    __shared__ half_t ts[64][136];
    const int tid = threadIdx.x;
    const int w = tid >> 6, l = tid & 63, g = l >> 4, ln = l & 15;
    const int r0 = blockIdx.x * 64;

    f32x4 acc[4][2];
    #pragma unroll
    for (int rf = 0; rf < 4; ++rf)
        #pragma unroll
        for (int cf = 0; cf < 2; ++cf) acc[rf][cf] = (f32x4)0.f;
    #pragma unroll
    for (int kk = 0; kk < 8; ++kk) {
        const int kb = kk * 16 + g * 4;
        half4_t a[4];
        #pragma unroll
        for (int rf = 0; rf < 4; ++rf) {
            int r = r0 + rf * 16 + ln;
            int rr = r < nrows ? r : nrows - 1;
            float4 av = *(const float4*)(A + (size_t)rr * 128 + kb);
            a[rf] = cvt4(av.x, av.y, av.z, av.w);
        }
        #pragma unroll
        for (int cf = 0; cf < 2; ++cf) {
            int n = w * 32 + cf * 16 + ln;
            half4_t b = *(const half4_t*)(Bt1 + (size_t)n * 128 + kb);
            #pragma unroll
            for (int rf = 0; rf < 4; ++rf)
                acc[rf][cf] = __builtin_amdgcn_mfma_f32_16x16x16f16(a[rf], b, acc[rf][cf], 0, 0, 0);
        }
    }
    #pragma unroll
    for (int cf = 0; cf < 2; ++cf) {
        int n = w * 32 + cf * 16 + ln;
        float bv = bias1[n];
        #pragma unroll
        for (int rf = 0; rf < 4; ++rf)
            #pragma unroll
            for (int reg = 0; reg < 4; ++reg)
                ts[rf*16 + g*4 + reg][n] = (half_t)sspf(acc[rf][cf][reg] + bv);
    }
    __syncthreads();

    f32x4 acc2[4][2];
    #pragma unroll
    for (int rf = 0; rf < 4; ++rf)
        #pragma unroll
        for (int cf = 0; cf < 2; ++cf) acc2[rf][cf] = (f32x4)0.f;
    #pragma unroll
    for (int kk = 0; kk < 8; ++kk) {
        const int kb = kk * 16 + g * 4;
        half4_t a[4];
        #pragma unroll
        for (int rf = 0; rf < 4; ++rf)
            a[rf] = *(const half4_t*)&ts[rf*16 + ln][kb];
        #pragma unroll
        for (int cf = 0; cf < 2; ++cf) {
            int n = w * 32 + cf * 16 + ln;
            half4_t b = *(const half4_t*)(Bt2 + (size_t)n * 128 + kb);
            #pragma unroll
            for (int rf = 0; rf < 4; ++rf)
                acc2[rf][cf] = __builtin_amdgcn_mfma_f32_16x16x16f16(a[rf], b, acc2[rf][cf], 0, 0, 0);
        }
    }
    #pragma unroll
    for (int cf = 0; cf < 2; ++cf) {
        int n = w * 32 + cf * 16 + ln;
        float bv = bias2[n];
        #pragma unroll
        for (int rf = 0; rf < 4; ++rf)
            #pragma unroll
            for (int reg = 0; reg < 4; ++reg) {
                int r = r0 + rf * 16 + g * 4 + reg;
                if (r < nrows) out[(size_t)r * 128 + n] = acc2[rf][cf][reg] + bv;
            }
    }
}

// R17 edge kernel: R13's dbuf-DMA pipeline over a pre-chunked stream.
// jv = linear int4 of pre-shifted byte offsets; meta = scalar word (atom,
// cnt, flush). rc via clamped loads + cnt mask (R13-proven).
__global__ __launch_bounds__(256, 2) void edge_kernel(
    const float* __restrict__ f_ij, const float* __restrict__ rcut,
    const int2* __restrict__ cmeta, const int* __restrict__ jvpk,
    const half_t* __restrict__ Wt_f1, const float* __restrict__ b1sc,
    const half_t* __restrict__ W2L, const float* __restrict__ b2a,
    const half_t* __restrict__ hh, float* __restrict__ agg,
    const int* __restrict__ chunk_off, int E, int N, int W)
{
    __shared__ __align__(16) half_t W2s[16384];        // 32768 B
    __shared__ __align__(16) half_t hsh[4][2][2048];   // 32768 B (dbuf, 4KB/wave)
    __shared__ float b1s[128];                         //   512 B

    const int tid = threadIdx.x;
    const int w = tid >> 6, l = tid & 63, g = l >> 4, ln = l & 15;

    for (int i = tid; i < 2048; i += 256)
        ((float4*)W2s)[i] = ((const float4*)W2L)[i];
    if (tid < 128) b1s[tid] = b1sc[tid];
    __syncthreads();

    // per-wave chunk range (balanced by chunks, atom-aligned)
    const int NC = chunk_off[N];
    const int kg = blockIdx.x * 4 + w;
    const int aLo = lbound(chunk_off, N + 1, (int)((size_t)kg * NC / W));
    const int aHi = (kg == W - 1) ? N
                  : lbound(chunk_off, N + 1, (int)((size_t)(kg + 1) * NC / W));
    int c  = __builtin_amdgcn_readfirstlane(chunk_off[aLo]);
    const int c1 = __builtin_amdgcn_readfirstlane(chunk_off[aHi]);
    if (c >= c1) return;

    // W1 A-frags in VGPRs (x32 stacked-K)
    half8_t w1f[8];
    #pragma unroll
    for (int rf = 0; rf < 8; ++rf) {
        half4_t lo = *(const half4_t*)(Wt_f1 + (size_t)(rf*16 + ln)*32 + g*4);
        half4_t hi = *(const half4_t*)(Wt_f1 + (size_t)(rf*16 + ln)*32 + 16 + g*4);
        w1f[rf] = __builtin_shufflevector(lo, hi, 0, 1, 2, 3, 4, 5, 6, 7);
    }

    // persistent b2' accumulator seeds (lane cols = ln*8 .. ln*8+7)
    f32x4 b2acc[8];
    {
        float4 blo4 = *(const float4*)(b2a + ln*8);
        float4 bhi4 = *(const float4*)(b2a + ln*8 + 4);
        float bv[8] = {blo4.x, blo4.y, blo4.z, blo4.w, bhi4.x, bhi4.y, bhi4.z, bhi4.w};
        #pragma unroll
        for (int q = 0; q < 8; ++q) {
            f32x4 t = {bv[q], bv[q], bv[q], bv[q]};
            b2acc[q] = t;
        }
    }

    const char* hb = (const char*)hh;
    const int sw0 = (ln ^ 0) << 4, sw1 = (ln ^ 1) << 4;
    const int sw2 = (ln ^ 2) << 4, sw3 = (ln ^ 3) << 4;

    // ---- prologue ----
    int4 jvC = *(const int4*)(jvpk + (size_t)c*16 + g*4);      // chunk c (DMA now)
    int2 mC  = cmeta[c];
    asm volatile("" ::: "memory");
    load_lds16(hb + (unsigned)jvC.x + sw0, &hsh[w][0][0]);
    load_lds16(hb + (unsigned)jvC.y + sw1, &hsh[w][0][512]);
    load_lds16(hb + (unsigned)jvC.z + sw2, &hsh[w][0][1024]);
    load_lds16(hb + (unsigned)jvC.w + sw3, &hsh[w][0][1536]);
    asm volatile("" ::: "memory");
    float4 fA, fB; float rc[4];
    {
        int cs0 = __builtin_amdgcn_readfirstlane(mC.x);
        int e = min(cs0 + ln, E - 1);
        fA = *(const float4*)(f_ij + (size_t)e*20 + g*4);
        fB = *(const float4*)(f_ij + (size_t)e*20 + 16);
        #pragma unroll
        for (int r2 = 0; r2 < 4; ++r2)
            rc[r2] = rcut[min(cs0 + 4*g + r2, E - 1)];
    }
    int m1cur = mC.y;
    int4 jvN = *(const int4*)(jvpk + (size_t)(c+1)*16 + g*4);
    int2 mN  = cmeta[c+1];
    asm volatile("" ::: "memory");

    float racc[8];
    #pragma unroll
    for (int q = 0; q < 8; ++q) racc[q] = 0.f;
    int p = 0;

    while (c < c1) {
        // ---- 1: DMA(c+1) into buf[p^1] (exactly 4 vmem between fences) ----
        asm volatile("" ::: "memory");
        {
            half_t* d = &hsh[w][p^1][0];
            load_lds16(hb + (unsigned)jvN.x + sw0, d);
            load_lds16(hb + (unsigned)jvN.y + sw1, d + 512);
            load_lds16(hb + (unsigned)jvN.z + sw2, d + 1024);
            load_lds16(hb + (unsigned)jvN.w + sw3, d + 1536);
        }
        // ---- 2: retire DMA(c) + all older prefetch loads ----
        asm volatile("s_waitcnt vmcnt(4)" ::: "memory");
        __builtin_amdgcn_sched_barrier(0);

        // ---- 3a: consume chunk-c state ----
        half4_t blo = cvt4(fA.x, fA.y, fA.z, fA.w);
        half4_t bhi;
        if (g == 0) bhi = cvt4(fB.x, fB.y, fB.z, fB.w);
        else { half4_t zz = {}; bhi = zz; }
        half8_t bf = __builtin_shufflevector(blo, bhi, 0, 1, 2, 3, 4, 5, 6, 7);
        const int mw  = __builtin_amdgcn_readfirstlane(m1cur);
        const int cnt = (mw >> 1) & 31;
        float rcm[4];
        #pragma unroll
        for (int r2 = 0; r2 < 4; ++r2)
            rcm[r2] = (4*g + r2 < cnt) ? rc[r2] : 0.f;

        // ---- 3b: prefetch chunk c+2 (jv, meta) and c+1 (f, rc) ----
        int4 jv2 = *(const int4*)(jvpk + (size_t)(c+2)*16 + g*4);
        int2 m2  = cmeta[c+2];
        float4 fA1, fB1; float rc1[4];
        {
            int csn = __builtin_amdgcn_readfirstlane(mN.x);
            int e = min(csn + ln, E - 1);
            fA1 = *(const float4*)(f_ij + (size_t)e*20 + g*4);
            fB1 = *(const float4*)(f_ij + (size_t)e*20 + 16);
            #pragma unroll
            for (int r2 = 0; r2 < 4; ++r2)
                rc1[r2] = rcut[min(csn + 4*g + r2, E - 1)];
        }
        asm volatile("" ::: "memory");

        // ---- 4: phase 1 (K=32) + folded softplus: a2 = log2(1 + 2^u) ----
        f32x4 z[8];
        #pragma unroll
        for (int rf = 0; rf < 8; ++rf)
            z[rf] = __builtin_amdgcn_mfma_f32_16x16x32_f16(w1f[rf], bf, (f32x4)0.f, 0, 0, 0);
        half8_t a2[4];
        #pragma unroll
        for (int t = 0; t < 4; ++t) {
            float4 bbA = *(const float4*)&b1s[(2*t)*16 + g*4];
            float4 bbB = *(const float4*)&b1s[(2*t+1)*16 + g*4];
            float l0 = __log2f(1.f + exp2f(fmaf(z[2*t][0],   LOG2EF, bbA.x)));
            float l1 = __log2f(1.f + exp2f(fmaf(z[2*t][1],   LOG2EF, bbA.y)));
            float l2 = __log2f(1.f + exp2f(fmaf(z[2*t][2],   LOG2EF, bbA.z)));
            float l3 = __log2f(1.f + exp2f(fmaf(z[2*t][3],   LOG2EF, bbA.w)));
            float l4 = __log2f(1.f + exp2f(fmaf(z[2*t+1][0], LOG2EF, bbB.x)));
            float l5 = __log2f(1.f + exp2f(fmaf(z[2*t+1][1], LOG2EF, bbB.y)));
            float l6 = __log2f(1.f + exp2f(fmaf(z[2*t+1][2], LOG2EF, bbB.z)));
            float l7 = __log2f(1.f + exp2f(fmaf(z[2*t+1][3], LOG2EF, bbB.w)));
            a2[t] = pk8(l0, l1, l2, l3, l4, l5, l6, l7);
        }

        // ---- 5: phase 2 (32 MFMA), acc seeded from persistent b2acc ----
        f32x4 acc[8];
        #pragma unroll
        for (int q = 0; q < 8; ++q) acc[q] = b2acc[q];
        __builtin_amdgcn_s_setprio(1);
        #pragma unroll
        for (int t = 0; t < 4; ++t)
            #pragma unroll
            for (int q = 0; q < 8; ++q) {
                half8_t bw = *(const half8_t*)&W2s[(((t*8 + q)*4 + g)*16 + ln)*8];
                acc[q] = __builtin_amdgcn_mfma_f32_16x16x32_f16(a2[t], bw, acc[q], 0, 0, 0);
            }
        __builtin_amdgcn_s_setprio(0);

        // ---- 6: epilogue — 4x ds_read_b128, rcm masks pads ----
        {
            const half_t* hb0 = &hsh[w][p][(4*g)*128 + ((ln ^ g) << 3)];
            half8_t h0 = *(const half8_t*)(hb0);
            half8_t h1 = *(const half8_t*)(hb0 + 128);
            half8_t h2 = *(const half8_t*)(hb0 + 256);
            half8_t h3 = *(const half8_t*)(hb0 + 384);
            #pragma unroll
            for (int q = 0; q < 8; ++q) {
                float s = racc[q];
                s = fmaf(acc[q][0] * rcm[0], (float)h0[q], s);
                s = fmaf(acc[q][1] * rcm[1], (float)h1[q], s);
                s = fmaf(acc[q][2] * rcm[2], (float)h2[q], s);
                s = fmaf(acc[q][3] * rcm[3], (float)h3[q], s);
                racc[q] = s;
            }
        }

        // ---- 7: atom flush (flush bit + atom id from scalar meta) ----
        if (mw & 1) {
            #pragma unroll
            for (int q = 0; q < 8; ++q) {
                float r = racc[q];
                r += __shfl_xor(r, 16, 64);
                r += __shfl_xor(r, 32, 64);
                racc[q] = r;
            }
            int arow = mw >> 6;
            if (g == 0) {
                float4 v0 = {racc[0], racc[1], racc[2], racc[3]};
                float4 v1 = {racc[4], racc[5], racc[6], racc[7]};
                *(float4*)(agg + (size_t)arow*128 + ln*8)     = v0;
                *(float4*)(agg + (size_t)arow*128 + ln*8 + 4) = v1;
            }
            #pragma unroll
            for (int q = 0; q < 8; ++q) racc[q] = 0.f;
        }

        // ---- 8: rotate state ----
        jvN = jv2; fA = fA1; fB = fB1;
        #pragma unroll
        for (int r2 = 0; r2 < 4; ++r2) rc[r2] = rc1[r2];
        m1cur = mN.y; mN = m2;
        p ^= 1; ++c;
    }
}

extern "C" void kernel_launch(void* const* d_in, const int* in_sizes, int n_in,
                              void* d_out, int out_size, void* d_ws, size_t ws_size,
                              hipStream_t stream)
{
    const float* x      = (const float*)d_in[0];
    const float* f_ij   = (const float*)d_in[1];
    const float* rcut   = (const float*)d_in[2];
    const int*   idx_i  = (const int*)d_in[3];
    const int*   idx_j  = (const int*)d_in[4];
    const float* W_in2f = (const float*)d_in[5];
    const float* W_f1   = (const float*)d_in[6];
    const float* b_f1   = (const float*)d_in[7];
    const float* W_f2   = (const float*)d_in[8];
    const float* b_f2   = (const float*)d_in[9];
    const float* W_o1   = (const float*)d_in[10];
    const float* b_o1   = (const float*)d_in[11];
    const float* W_o2   = (const float*)d_in[12];
    const float* b_o2   = (const float*)d_in[13];

    const int N = in_sizes[0] / 128;
    const int E = in_sizes[2];
    const int NCMAX = E/16 + N + 8;

    half_t* h16  = (half_t*)d_ws;                       // [N,128] f16
    half_t* wt   = (half_t*)((char*)d_ws + (size_t)N * 128 * 2);
    half_t* Wt_in2f = wt;                 // 16384 halfs
    half_t* Wt_f1   = wt + 16384;         //  4096
    half_t* W2L     = wt + 16384 + 4096;  // 16384
    half_t* Wt_o1   = W2L + 16384;        // 16384
    half_t* Wt_o2   = Wt_o1 + 16384;      // 16384
    float*  b1sc    = (float*)(Wt_o2 + 16384);          // 128 floats
    float*  b2a     = b1sc + 128;                       // 128 floats
    int* atom_start = (int*)(b2a + 128);                // N+1 ints
    int* chunk_off  = atom_start + (N + 1);             // N+1 ints
    int* ip = chunk_off + (N + 1);
    if (((uintptr_t)ip) & 7) ++ip;                      // align int2
    int2*  cmeta = (int2*)ip;                           // NCMAX int2
    int*   jvpk  = (int*)(cmeta + NCMAX);               // NCMAX*16 ints

    prep_weights<<<273, 256, 0, stream>>>(W_in2f, W_f1, W_f2, W_o1, W_o2,
                                          b_f1, b_f2,
                                          Wt_in2f, Wt_f1, W2L, Wt_o1, Wt_o2,
                                          b1sc, b2a);
    seg_starts<<<(E + 255) / 256, 256, 0, stream>>>(idx_i, atom_start, E, N);
    chunk_scan<<<1, 256, 0, stream>>>(atom_start, chunk_off, N);
    chunk_atoms<<<(N + 255) / 256, 256, 0, stream>>>(atom_start, chunk_off, cmeta, N);
    chunk_edges<<<(NCMAX * 16 + 255) / 256, 256, 0, stream>>>(
        idx_j, chunk_off, cmeta, jvpk, N, NCMAX);

    const int gn  = (N + 63) / 64;
    const int nbl = 512;                  // 4 waves/block, 2 blocks/CU
    const int W   = nbl * 4;

    // h = x @ W_in2f -> f16
    mfma_gemm_h<<<gn, 256, 0, stream>>>(x, Wt_in2f, h16, N);

    // pre-chunked wave-independent edge pipeline -> agg
    edge_kernel<<<nbl, 256, 0, stream>>>(f_ij, rcut, cmeta, jvpk,
                                         Wt_f1, b1sc, W2L, b2a,
                                         h16, (float*)d_out, chunk_off, E, N, W);

    // out = ssp(agg @ W_o1 + b_o1) @ W_o2 + b_o2   (fused, in-place on d_out)
    mfma_gemm2<<<gn, 256, 0, stream>>>((const float*)d_out, Wt_o1, b_o1,
                                       Wt_o2, b_o2, (float*)d_out, N);
}

// Round 18
// 282.679 us; speedup vs baseline: 1.2415x; 1.2415x over previous
//
#include <hip/hip_runtime.h>
#include <math.h>

#define LN2F 0.6931471805599453f
#define LOG2EF 1.4426950408889634f

typedef _Float16 half_t;
typedef _Float16 half4_t __attribute__((ext_vector_type(4)));
typedef _Float16 half8_t __attribute__((ext_vector_type(8)));
typedef __fp16 fp16x2 __attribute__((ext_vector_type(2)));
typedef __fp16 fp16x4 __attribute__((ext_vector_type(4)));
typedef __fp16 fp16x8 __attribute__((ext_vector_type(8)));
typedef float f32x4 __attribute__((ext_vector_type(4)));

__device__ __forceinline__ float sspf(float z) {
    return fmaxf(z, 0.f) + __logf(1.f + __expf(-fabsf(z))) - LN2F;
}
__device__ __forceinline__ half4_t cvt4(float x, float y, float z, float w) {
    half4_t r; r[0]=(half_t)x; r[1]=(half_t)y; r[2]=(half_t)z; r[3]=(half_t)w; return r;
}
__device__ __forceinline__ half8_t pk8(float a, float b, float c, float d,
                                       float e, float f, float g, float h) {
    fp16x2 p0 = __builtin_amdgcn_cvt_pkrtz(a, b);
    fp16x2 p1 = __builtin_amdgcn_cvt_pkrtz(c, d);
    fp16x2 p2 = __builtin_amdgcn_cvt_pkrtz(e, f);
    fp16x2 p3 = __builtin_amdgcn_cvt_pkrtz(g, h);
    fp16x4 lo = __builtin_shufflevector(p0, p1, 0, 1, 2, 3);
    fp16x4 hi = __builtin_shufflevector(p2, p3, 0, 1, 2, 3);
    fp16x8 v  = __builtin_shufflevector(lo, hi, 0, 1, 2, 3, 4, 5, 6, 7);
    return __builtin_bit_cast(half8_t, v);
}

// async global->LDS DMA, 16 B per lane; dest = wave-uniform base + lane*16
__device__ __forceinline__ void load_lds16(const void* g, void* l) {
    __builtin_amdgcn_global_load_lds(
        (const __attribute__((address_space(1))) unsigned int*)g,
        (__attribute__((address_space(3))) unsigned int*)l, 16, 0, 0);
}

__device__ __forceinline__ int lbound(const int* __restrict__ a, int n, int key) {
    int lo = 0, hi = n;
    while (lo < hi) { int m = (lo + hi) >> 1; if (a[m] < key) lo = m + 1; else hi = m; }
    return lo;
}

// ---- weight prep (layouts validated R12/R13) ----
__global__ __launch_bounds__(256) void prep_weights(
    const float* __restrict__ W_in2f, const float* __restrict__ W_f1,
    const float* __restrict__ W_f2, const float* __restrict__ W_o1,
    const float* __restrict__ W_o2,
    const float* __restrict__ b_f1, const float* __restrict__ b_f2,
    half_t* __restrict__ Wt_in2f, half_t* __restrict__ Wt_f1,
    half_t* __restrict__ W2L, half_t* __restrict__ Wt_o1,
    half_t* __restrict__ Wt_o2, float* __restrict__ b1sc, float* __restrict__ b2a)
{
    int b = blockIdx.x;
    if (b < 64) {
        int i = b*256 + threadIdx.x;
        Wt_in2f[i] = (half_t)W_in2f[(i & 127)*128 + (i >> 7)];
    } else if (b < 80) {
        int i = (b-64)*256 + threadIdx.x;
        int n = i >> 5, k = i & 31;
        Wt_f1[i] = (k < 20) ? (half_t)W_f1[k*128 + n] : (half_t)0.f;
    } else if (b < 144) {
        int i = (b-80)*256 + threadIdx.x;     // 0..16383
        int j = i & 7, ln = (i >> 3) & 15, g = (i >> 7) & 3;
        int nt = (i >> 9) & 7, t = i >> 12;
        int k = 32*t + ((j < 4) ? (g*4 + j) : (16 + g*4 + (j - 4)));
        W2L[i] = (half_t)(LN2F * W_f2[k*128 + ln*8 + nt]);
    } else if (b < 208) {
        int i = (b-144)*256 + threadIdx.x;
        Wt_o1[i] = (half_t)W_o1[(i & 127)*128 + (i >> 7)];
    } else if (b < 272) {
        int i = (b-208)*256 + threadIdx.x;
        Wt_o2[i] = (half_t)W_o2[(i & 127)*128 + (i >> 7)];
    } else {
        int c = threadIdx.x;
        if (c < 128) {
            float s = 0.f;
            for (int k = 0; k < 128; ++k) s += W_f2[k*128 + c];
            b2a[c]  = b_f2[c] - LN2F * s;
            b1sc[c] = b_f1[c] * LOG2EF;
        }
    }
}

// atom_start[a] = first edge index with idx_i >= a; atom_start[N] = E
__global__ __launch_bounds__(256) void seg_starts(
    const int* __restrict__ idx_i, int* __restrict__ atom_start, int E, int N)
{
    int e = blockIdx.x * 256 + threadIdx.x;
    if (e >= E) return;
    int a = idx_i[e];
    int prev = (e == 0) ? -1 : idx_i[e - 1];
    for (int k = prev + 1; k <= a; ++k) atom_start[k] = e;
    if (e == E - 1)
        for (int k = a + 1; k <= N; ++k) atom_start[k] = E;
}

// scanA: per-block (256 atoms) sum of chunk counts -> bsum[b]
__global__ __launch_bounds__(256) void scanA(
    const int* __restrict__ atom_start, int* __restrict__ bsum, int N)
{
    __shared__ int s[256];
    int t = threadIdx.x;
    int a = blockIdx.x * 256 + t;
    int cnt = 0;
    if (a < N) {
        int deg = atom_start[a+1] - atom_start[a];
        cnt = max(1, (deg + 15) >> 4);
    }
    s[t] = cnt;
    __syncthreads();
    #pragma unroll
    for (int st = 128; st > 0; st >>= 1) {
        if (t < st) s[t] += s[t + st];
        __syncthreads();
    }
    if (t == 0) bsum[blockIdx.x] = s[0];
}

// scanB: serial scan of bsum (NB ~ 196 entries), total -> chunk_off[N];
// writes poison-proof pad records beyond NC.
__global__ __launch_bounds__(64) void scanB(
    const int* __restrict__ bsum, int* __restrict__ bbase,
    int* __restrict__ chunk_off, int2* __restrict__ cmeta,
    int* __restrict__ jvpk, int NB, int N)
{
    __shared__ int NCs;
    if (threadIdx.x == 0) {
        int acc = 0;
        for (int b = 0; b < NB; ++b) { bbase[b] = acc; acc += bsum[b]; }
        chunk_off[N] = acc;
        NCs = acc;
    }
    __syncthreads();
    int NC = NCs;
    jvpk[(size_t)NC*16 + threadIdx.x] = 0;            // pads chunks NC..NC+3
    if (threadIdx.x < 4) cmeta[NC + threadIdx.x] = make_int2(0, 0);
}

// chunk_fill: intra-block scan -> chunk_off[a]; write cmeta + permuted jvpk
// for this atom's chunks (fused old chunk_atoms + chunk_edges).
__global__ __launch_bounds__(256) void chunk_fill(
    const int* __restrict__ atom_start, const int* __restrict__ bbase,
    const int* __restrict__ idx_j, int* __restrict__ chunk_off,
    int2* __restrict__ cmeta, int* __restrict__ jvpk, int N)
{
    __shared__ int s[256];
    int t = threadIdx.x;
    int a = blockIdx.x * 256 + t;
    int cnt = 0, st0 = 0, e1 = 0;
    if (a < N) {
        st0 = atom_start[a]; e1 = atom_start[a+1];
        cnt = max(1, (e1 - st0 + 15) >> 4);
    }
    s[t] = cnt;
    __syncthreads();
    // Hillis-Steele inclusive scan
    for (int off = 1; off < 256; off <<= 1) {
        int x = s[t];
        int y = (t >= off) ? s[t - off] : 0;
        __syncthreads();
        s[t] = x + y;
        __syncthreads();
    }
    if (a < N) {
        int c0 = bbase[blockIdx.x] + s[t] - cnt;
        chunk_off[a] = c0;
        for (int k = 0; k < cnt; ++k) {
            int cs = st0 + 16*k;
            int cc = e1 - cs; cc = cc < 0 ? 0 : (cc > 16 ? 16 : cc);
            cmeta[c0+k] = make_int2(cs, (a << 6) | (cc << 1) | (k == cnt-1 ? 1 : 0));
            int* jp = jvpk + (size_t)(c0+k)*16;
            #pragma unroll
            for (int ss = 0; ss < 16; ++ss) {
                int off2 = 4*(ss & 3) + (ss >> 2);      // edge = cs + 4*it + g
                jp[ss] = (off2 < cc) ? (idx_j[cs + off2] << 8) : 0;
            }
        }
    }
}

// h = x @ W_in2f -> f16
__global__ __launch_bounds__(256) void mfma_gemm_h(
    const float* __restrict__ A, const half_t* __restrict__ Bt,
    half_t* __restrict__ Ch, int nrows)
{
    const int tid = threadIdx.x;
    const int w = tid >> 6, l = tid & 63, g = l >> 4, ln = l & 15;
    const int r0 = blockIdx.x * 64;

    f32x4 acc[4][2];
    #pragma unroll
    for (int rf = 0; rf < 4; ++rf)
        #pragma unroll
        for (int cf = 0; cf < 2; ++cf) acc[rf][cf] = (f32x4)0.f;

    #pragma unroll
    for (int kk = 0; kk < 8; ++kk) {
        const int kb = kk * 16 + g * 4;
        half4_t a[4];
        #pragma unroll
        for (int rf = 0; rf < 4; ++rf) {
            int r = r0 + rf * 16 + ln;
            int rr = r < nrows ? r : nrows - 1;
            float4 av = *(const float4*)(A + (size_t)rr * 128 + kb);
            a[rf] = cvt4(av.x, av.y, av.z, av.w);
        }
        #pragma unroll
        for (int cf = 0; cf < 2; ++cf) {
            int n = w * 32 + cf * 16 + ln;
            half4_t b = *(const half4_t*)(Bt + (size_t)n * 128 + kb);
            #pragma unroll
            for (int rf = 0; rf < 4; ++rf)
                acc[rf][cf] = __builtin_amdgcn_mfma_f32_16x16x16f16(a[rf], b, acc[rf][cf], 0, 0, 0);
        }
    }
    #pragma unroll
    for (int cf = 0; cf < 2; ++cf) {
        int n = w * 32 + cf * 16 + ln;
        #pragma unroll
        for (int rf = 0; rf < 4; ++rf)
            #pragma unroll
            for (int reg = 0; reg < 4; ++reg) {
                int r = r0 + rf * 16 + g * 4 + reg;
                if (r < nrows) Ch[(size_t)r * 128 + n] = (half_t)acc[rf][cf][reg];
            }
    }
}

// fused out-MLP: out = ssp(agg@O1+b1)@O2+b2
__global__ __launch_bounds__(256) void mfma_gemm2(
    const float* __restrict__ A, const half_t* __restrict__ Bt1,
    const float* __restrict__ bias1, const half_t* __restrict__ Bt2,
    const float* __restrict__ bias2, float* __restrict__ out, int nrows)
{
    __shared__ half_t ts[64][136];
    const int tid = threadIdx.x;
    const int w = tid >> 6, l = tid & 63, g = l >> 4, ln = l & 15;
    const int r0 = blockIdx.x * 64;

    f32x4 acc[4][2];
    #pragma unroll
    for (int rf = 0; rf < 4; ++rf)
        #pragma unroll
        for (int cf = 0; cf < 2; ++cf) acc[rf][cf] = (f32x4)0.f;
    #pragma unroll
    for (int kk = 0; kk < 8; ++kk) {
        const int kb = kk * 16 + g * 4;
        half4_t a[4];
        #pragma unroll
        for (int rf = 0; rf < 4; ++rf) {
            int r = r0 + rf * 16 + ln;
            int rr = r < nrows ? r : nrows - 1;
            float4 av = *(const float4*)(A + (size_t)rr * 128 + kb);
            a[rf] = cvt4(av.x, av.y, av.z, av.w);
        }
        #pragma unroll
        for (int cf = 0; cf < 2; ++cf) {
            int n = w * 32 + cf * 16 + ln;
            half4_t b = *(const half4_t*)(Bt1 + (size_t)n * 128 + kb);
            #pragma unroll
            for (int rf = 0; rf < 4; ++rf)
                acc[rf][cf] = __builtin_amdgcn_mfma_f32_16x16x16f16(a[rf], b, acc[rf][cf], 0, 0, 0);
        }
    }
    #pragma unroll
    for (int cf = 0; cf < 2; ++cf) {
        int n = w * 32 + cf * 16 + ln;
        float bv = bias1[n];
        #pragma unroll
        for (int rf = 0; rf < 4; ++rf)
            #pragma unroll
            for (int reg = 0; reg < 4; ++reg)
                ts[rf*16 + g*4 + reg][n] = (half_t)sspf(acc[rf][cf][reg] + bv);
    }
    __syncthreads();

    f32x4 acc2[4][2];
    #pragma unroll
    for (int rf = 0; rf < 4; ++rf)
        #pragma unroll
        for (int cf = 0; cf < 2; ++cf) acc2[rf][cf] = (f32x4)0.f;
    #pragma unroll
    for (int kk = 0; kk < 8; ++kk) {
        const int kb = kk * 16 + g * 4;
        half4_t a[4];
        #pragma unroll
        for (int rf = 0; rf < 4; ++rf)
            a[rf] = *(const half4_t*)&ts[rf*16 + ln][kb];
        #pragma unroll
        for (int cf = 0; cf < 2; ++cf) {
            int n = w * 32 + cf * 16 + ln;
            half4_t b = *(const half4_t*)(Bt2 + (size_t)n * 128 + kb);
            #pragma unroll
            for (int rf = 0; rf < 4; ++rf)
                acc2[rf][cf] = __builtin_amdgcn_mfma_f32_16x16x16f16(a[rf], b, acc2[rf][cf], 0, 0, 0);
        }
    }
    #pragma unroll
    for (int cf = 0; cf < 2; ++cf) {
        int n = w * 32 + cf * 16 + ln;
        float bv = bias2[n];
        #pragma unroll
        for (int rf = 0; rf < 4; ++rf)
            #pragma unroll
            for (int reg = 0; reg < 4; ++reg) {
                int r = r0 + rf * 16 + g * 4 + reg;
                if (r < nrows) out[(size_t)r * 128 + n] = acc2[rf][cf][reg] + bv;
            }
    }
}

// R18 edge kernel: identical to validated R17.
__global__ __launch_bounds__(256, 2) void edge_kernel(
    const float* __restrict__ f_ij, const float* __restrict__ rcut,
    const int2* __restrict__ cmeta, const int* __restrict__ jvpk,
    const half_t* __restrict__ Wt_f1, const float* __restrict__ b1sc,
    const half_t* __restrict__ W2L, const float* __restrict__ b2a,
    const half_t* __restrict__ hh, float* __restrict__ agg,
    const int* __restrict__ chunk_off, int E, int N, int W)
{
    __shared__ __align__(16) half_t W2s[16384];        // 32768 B
    __shared__ __align__(16) half_t hsh[4][2][2048];   // 32768 B (dbuf, 4KB/wave)
    __shared__ float b1s[128];                         //   512 B

    const int tid = threadIdx.x;
    const int w = tid >> 6, l = tid & 63, g = l >> 4, ln = l & 15;

    for (int i = tid; i < 2048; i += 256)
        ((float4*)W2s)[i] = ((const float4*)W2L)[i];
    if (tid < 128) b1s[tid] = b1sc[tid];
    __syncthreads();

    // per-wave chunk range (balanced by chunks, atom-aligned)
    const int NC = chunk_off[N];
    const int kg = blockIdx.x * 4 + w;
    const int aLo = lbound(chunk_off, N + 1, (int)((size_t)kg * NC / W));
    const int aHi = (kg == W - 1) ? N
                  : lbound(chunk_off, N + 1, (int)((size_t)(kg + 1) * NC / W));
    int c  = __builtin_amdgcn_readfirstlane(chunk_off[aLo]);
    const int c1 = __builtin_amdgcn_readfirstlane(chunk_off[aHi]);
    if (c >= c1) return;

    // W1 A-frags in VGPRs (x32 stacked-K)
    half8_t w1f[8];
    #pragma unroll
    for (int rf = 0; rf < 8; ++rf) {
        half4_t lo = *(const half4_t*)(Wt_f1 + (size_t)(rf*16 + ln)*32 + g*4);
        half4_t hi = *(const half4_t*)(Wt_f1 + (size_t)(rf*16 + ln)*32 + 16 + g*4);
        w1f[rf] = __builtin_shufflevector(lo, hi, 0, 1, 2, 3, 4, 5, 6, 7);
    }

    // persistent b2' accumulator seeds (lane cols = ln*8 .. ln*8+7)
    f32x4 b2acc[8];
    {
        float4 blo4 = *(const float4*)(b2a + ln*8);
        float4 bhi4 = *(const float4*)(b2a + ln*8 + 4);
        float bv[8] = {blo4.x, blo4.y, blo4.z, blo4.w, bhi4.x, bhi4.y, bhi4.z, bhi4.w};
        #pragma unroll
        for (int q = 0; q < 8; ++q) {
            f32x4 t = {bv[q], bv[q], bv[q], bv[q]};
            b2acc[q] = t;
        }
    }

    const char* hb = (const char*)hh;
    const int sw0 = (ln ^ 0) << 4, sw1 = (ln ^ 1) << 4;
    const int sw2 = (ln ^ 2) << 4, sw3 = (ln ^ 3) << 4;

    // ---- prologue ----
    int4 jvC = *(const int4*)(jvpk + (size_t)c*16 + g*4);      // chunk c (DMA now)
    int2 mC  = cmeta[c];
    asm volatile("" ::: "memory");
    load_lds16(hb + (unsigned)jvC.x + sw0, &hsh[w][0][0]);
    load_lds16(hb + (unsigned)jvC.y + sw1, &hsh[w][0][512]);
    load_lds16(hb + (unsigned)jvC.z + sw2, &hsh[w][0][1024]);
    load_lds16(hb + (unsigned)jvC.w + sw3, &hsh[w][0][1536]);
    asm volatile("" ::: "memory");
    float4 fA, fB; float rc[4];
    {
        int cs0 = __builtin_amdgcn_readfirstlane(mC.x);
        int e = min(cs0 + ln, E - 1);
        fA = *(const float4*)(f_ij + (size_t)e*20 + g*4);
        fB = *(const float4*)(f_ij + (size_t)e*20 + 16);
        #pragma unroll
        for (int r2 = 0; r2 < 4; ++r2)
            rc[r2] = rcut[min(cs0 + 4*g + r2, E - 1)];
    }
    int m1cur = mC.y;
    int4 jvN = *(const int4*)(jvpk + (size_t)(c+1)*16 + g*4);
    int2 mN  = cmeta[c+1];
    asm volatile("" ::: "memory");

    float racc[8];
    #pragma unroll
    for (int q = 0; q < 8; ++q) racc[q] = 0.f;
    int p = 0;

    while (c < c1) {
        // ---- 1: DMA(c+1) into buf[p^1] (exactly 4 vmem between fences) ----
        asm volatile("" ::: "memory");
        {
            half_t* d = &hsh[w][p^1][0];
            load_lds16(hb + (unsigned)jvN.x + sw0, d);
            load_lds16(hb + (unsigned)jvN.y + sw1, d + 512);
            load_lds16(hb + (unsigned)jvN.z + sw2, d + 1024);
            load_lds16(hb + (unsigned)jvN.w + sw3, d + 1536);
        }
        // ---- 2: retire DMA(c) + all older prefetch loads ----
        asm volatile("s_waitcnt vmcnt(4)" ::: "memory");
        __builtin_amdgcn_sched_barrier(0);

        // ---- 3a: consume chunk-c state ----
        half4_t blo = cvt4(fA.x, fA.y, fA.z, fA.w);
        half4_t bhi;
        if (g == 0) bhi = cvt4(fB.x, fB.y, fB.z, fB.w);
        else { half4_t zz = {}; bhi = zz; }
        half8_t bf = __builtin_shufflevector(blo, bhi, 0, 1, 2, 3, 4, 5, 6, 7);
        const int mw  = __builtin_amdgcn_readfirstlane(m1cur);
        const int cnt = (mw >> 1) & 31;
        float rcm[4];
        #pragma unroll
        for (int r2 = 0; r2 < 4; ++r2)
            rcm[r2] = (4*g + r2 < cnt) ? rc[r2] : 0.f;

        // ---- 3b: prefetch chunk c+2 (jv, meta) and c+1 (f, rc) ----
        int4 jv2 = *(const int4*)(jvpk + (size_t)(c+2)*16 + g*4);
        int2 m2  = cmeta[c+2];
        float4 fA1, fB1; float rc1[4];
        {
            int csn = __builtin_amdgcn_readfirstlane(mN.x);
            int e = min(csn + ln, E - 1);
            fA1 = *(const float4*)(f_ij + (size_t)e*20 + g*4);
            fB1 = *(const float4*)(f_ij + (size_t)e*20 + 16);
            #pragma unroll
            for (int r2 = 0; r2 < 4; ++r2)
                rc1[r2] = rcut[min(csn + 4*g + r2, E - 1)];
        }
        asm volatile("" ::: "memory");

        // ---- 4: phase 1 (K=32) + folded softplus: a2 = log2(1 + 2^u) ----
        f32x4 z[8];
        #pragma unroll
        for (int rf = 0; rf < 8; ++rf)
            z[rf] = __builtin_amdgcn_mfma_f32_16x16x32_f16(w1f[rf], bf, (f32x4)0.f, 0, 0, 0);
        half8_t a2[4];
        #pragma unroll
        for (int t = 0; t < 4; ++t) {
            float4 bbA = *(const float4*)&b1s[(2*t)*16 + g*4];
            float4 bbB = *(const float4*)&b1s[(2*t+1)*16 + g*4];
            float l0 = __log2f(1.f + exp2f(fmaf(z[2*t][0],   LOG2EF, bbA.x)));
            float l1 = __log2f(1.f + exp2f(fmaf(z[2*t][1],   LOG2EF, bbA.y)));
            float l2 = __log2f(1.f + exp2f(fmaf(z[2*t][2],   LOG2EF, bbA.z)));
            float l3 = __log2f(1.f + exp2f(fmaf(z[2*t][3],   LOG2EF, bbA.w)));
            float l4 = __log2f(1.f + exp2f(fmaf(z[2*t+1][0], LOG2EF, bbB.x)));
            float l5 = __log2f(1.f + exp2f(fmaf(z[2*t+1][1], LOG2EF, bbB.y)));
            float l6 = __log2f(1.f + exp2f(fmaf(z[2*t+1][2], LOG2EF, bbB.z)));
            float l7 = __log2f(1.f + exp2f(fmaf(z[2*t+1][3], LOG2EF, bbB.w)));
            a2[t] = pk8(l0, l1, l2, l3, l4, l5, l6, l7);
        }

        // ---- 5: phase 2 (32 MFMA), acc seeded from persistent b2acc ----
        f32x4 acc[8];
        #pragma unroll
        for (int q = 0; q < 8; ++q) acc[q] = b2acc[q];
        __builtin_amdgcn_s_setprio(1);
        #pragma unroll
        for (int t = 0; t < 4; ++t)
            #pragma unroll
            for (int q = 0; q < 8; ++q) {
                half8_t bw = *(const half8_t*)&W2s[(((t*8 + q)*4 + g)*16 + ln)*8];
                acc[q] = __builtin_amdgcn_mfma_f32_16x16x32_f16(a2[t], bw, acc[q], 0, 0, 0);
            }
        __builtin_amdgcn_s_setprio(0);

        // ---- 6: epilogue — 4x ds_read_b128, rcm masks pads ----
        {
            const half_t* hb0 = &hsh[w][p][(4*g)*128 + ((ln ^ g) << 3)];
            half8_t h0 = *(const half8_t*)(hb0);
            half8_t h1 = *(const half8_t*)(hb0 + 128);
            half8_t h2 = *(const half8_t*)(hb0 + 256);
            half8_t h3 = *(const half8_t*)(hb0 + 384);
            #pragma unroll
            for (int q = 0; q < 8; ++q) {
                float s = racc[q];
                s = fmaf(acc[q][0] * rcm[0], (float)h0[q], s);
                s = fmaf(acc[q][1] * rcm[1], (float)h1[q], s);
                s = fmaf(acc[q][2] * rcm[2], (float)h2[q], s);
                s = fmaf(acc[q][3] * rcm[3], (float)h3[q], s);
                racc[q] = s;
            }
        }

        // ---- 7: atom flush (flush bit + atom id from scalar meta) ----
        if (mw & 1) {
            #pragma unroll
            for (int q = 0; q < 8; ++q) {
                float r = racc[q];
                r += __shfl_xor(r, 16, 64);
                r += __shfl_xor(r, 32, 64);
                racc[q] = r;
            }
            int arow = mw >> 6;
            if (g == 0) {
                float4 v0 = {racc[0], racc[1], racc[2], racc[3]};
                float4 v1 = {racc[4], racc[5], racc[6], racc[7]};
                *(float4*)(agg + (size_t)arow*128 + ln*8)     = v0;
                *(float4*)(agg + (size_t)arow*128 + ln*8 + 4) = v1;
            }
            #pragma unroll
            for (int q = 0; q < 8; ++q) racc[q] = 0.f;
        }

        // ---- 8: rotate state ----
        jvN = jv2; fA = fA1; fB = fB1;
        #pragma unroll
        for (int r2 = 0; r2 < 4; ++r2) rc[r2] = rc1[r2];
        m1cur = mN.y; mN = m2;
        p ^= 1; ++c;
    }
}

extern "C" void kernel_launch(void* const* d_in, const int* in_sizes, int n_in,
                              void* d_out, int out_size, void* d_ws, size_t ws_size,
                              hipStream_t stream)
{
    const float* x      = (const float*)d_in[0];
    const float* f_ij   = (const float*)d_in[1];
    const float* rcut   = (const float*)d_in[2];
    const int*   idx_i  = (const int*)d_in[3];
    const int*   idx_j  = (const int*)d_in[4];
    const float* W_in2f = (const float*)d_in[5];
    const float* W_f1   = (const float*)d_in[6];
    const float* b_f1   = (const float*)d_in[7];
    const float* W_f2   = (const float*)d_in[8];
    const float* b_f2   = (const float*)d_in[9];
    const float* W_o1   = (const float*)d_in[10];
    const float* b_o1   = (const float*)d_in[11];
    const float* W_o2   = (const float*)d_in[12];
    const float* b_o2   = (const float*)d_in[13];

    const int N = in_sizes[0] / 128;
    const int E = in_sizes[2];
    const int NB = (N + 255) / 256;
    const int NCMAX = E/16 + N + 8;

    half_t* h16  = (half_t*)d_ws;                       // [N,128] f16
    half_t* wt   = (half_t*)((char*)d_ws + (size_t)N * 128 * 2);
    half_t* Wt_in2f = wt;                 // 16384 halfs
    half_t* Wt_f1   = wt + 16384;         //  4096
    half_t* W2L     = wt + 16384 + 4096;  // 16384
    half_t* Wt_o1   = W2L + 16384;        // 16384
    half_t* Wt_o2   = Wt_o1 + 16384;      // 16384
    float*  b1sc    = (float*)(Wt_o2 + 16384);          // 128 floats
    float*  b2a     = b1sc + 128;                       // 128 floats
    int* atom_start = (int*)(b2a + 128);                // N+1 ints
    int* chunk_off  = atom_start + (N + 1);             // N+1 ints
    int* bsum       = chunk_off + (N + 1);              // NB ints
    int* bbase      = bsum + NB;                        // NB ints
    int* ip = bbase + NB;
    if (((uintptr_t)ip) & 7) ++ip;                      // align int2
    int2*  cmeta = (int2*)ip;                           // NCMAX int2
    int*   jvpk  = (int*)(cmeta + NCMAX);               // NCMAX*16 ints

    prep_weights<<<273, 256, 0, stream>>>(W_in2f, W_f1, W_f2, W_o1, W_o2,
                                          b_f1, b_f2,
                                          Wt_in2f, Wt_f1, W2L, Wt_o1, Wt_o2,
                                          b1sc, b2a);
    seg_starts<<<(E + 255) / 256, 256, 0, stream>>>(idx_i, atom_start, E, N);
    scanA<<<NB, 256, 0, stream>>>(atom_start, bsum, N);
    scanB<<<1, 64, 0, stream>>>(bsum, bbase, chunk_off, cmeta, jvpk, NB, N);
    chunk_fill<<<NB, 256, 0, stream>>>(atom_start, bbase, idx_j,
                                       chunk_off, cmeta, jvpk, N);

    const int gn  = (N + 63) / 64;
    const int nbl = 512;                  // 4 waves/block, 2 blocks/CU
    const int W   = nbl * 4;

    // h = x @ W_in2f -> f16
    mfma_gemm_h<<<gn, 256, 0, stream>>>(x, Wt_in2f, h16, N);

    // pre-chunked wave-independent edge pipeline -> agg
    edge_kernel<<<nbl, 256, 0, stream>>>(f_ij, rcut, cmeta, jvpk,
                                         Wt_f1, b1sc, W2L, b2a,
                                         h16, (float*)d_out, chunk_off, E, N, W);

    // out = ssp(agg @ W_o1 + b_o1) @ W_o2 + b_o2   (fused, in-place on d_out)
    mfma_gemm2<<<gn, 256, 0, stream>>>((const float*)d_out, Wt_o1, b_o1,
                                       Wt_o2, b_o2, (float*)d_out, N);
}